// Round 1
// baseline (186.552 us; speedup 1.0000x reference)
//
#include <hip/hip_runtime.h>

#define NB   8192
#define HW   4096   // 64*64
#define WDIM 64

// Order-preserving float->uint map: u1 > u2  <=>  f1 > f2 (for non-NaN).
__device__ __forceinline__ unsigned int fkey(float v) {
    unsigned int u = __float_as_uint(v);
    return (u & 0x80000000u) ? ~u : (u | 0x80000000u);
}

__global__ __launch_bounds__(256) void per_sample_loss(const float* __restrict__ x,
                                                       float* __restrict__ ws) {
    const int b = blockIdx.x;
    const int t = threadIdx.x;
    const float4* xp = (const float4*)(x + (size_t)b * HW);

    float s0 = 0.f, sj = 0.f, sk = 0.f, sq = 0.f;
    unsigned long long bestKey = 0ull;

#pragma unroll
    for (int i = 0; i < 4; ++i) {
        const int vecIdx = i * 256 + t;        // 0..1023, coalesced across lanes
        const float4 v4 = xp[vecIdx];
        const int e0 = vecIdx * 4;
        const float vv[4] = {v4.x, v4.y, v4.z, v4.w};
#pragma unroll
        for (int c = 0; c < 4; ++c) {
            const int e = e0 + c;              // flat index in sample, 0..4095
            const float v = vv[c];
            const float jf = (float)(e >> 6);
            const float kf = (float)(e & 63);
            s0 += v;
            sj = fmaf(jf, v, sj);
            sk = fmaf(kf, v, sk);
            sq = fmaf(fmaf(jf, jf, kf * kf), v, sq);
            // max key = max value; on value tie, larger (4095-e) => smaller e (first max)
            const unsigned long long key =
                ((unsigned long long)fkey(v) << 32) | (unsigned int)(HW - 1 - e);
            bestKey = key > bestKey ? key : bestKey;
        }
    }

    // wave-level reduction (64 lanes)
#pragma unroll
    for (int off = 32; off > 0; off >>= 1) {
        s0 += __shfl_down(s0, off);
        sj += __shfl_down(sj, off);
        sk += __shfl_down(sk, off);
        sq += __shfl_down(sq, off);
        const unsigned long long o = __shfl_down(bestKey, off);
        bestKey = o > bestKey ? o : bestKey;
    }

    __shared__ float ls0[4], lsj[4], lsk[4], lsq[4];
    __shared__ unsigned long long lk[4];
    const int wave = t >> 6;
    if ((t & 63) == 0) {
        ls0[wave] = s0; lsj[wave] = sj; lsk[wave] = sk; lsq[wave] = sq;
        lk[wave] = bestKey;
    }
    __syncthreads();

    if (t == 0) {
        float S0 = 0.f, Sj = 0.f, Sk = 0.f, Sq = 0.f;
        unsigned long long K = 0ull;
#pragma unroll
        for (int w = 0; w < 4; ++w) {
            S0 += ls0[w]; Sj += lsj[w]; Sk += lsk[w]; Sq += lsq[w];
            K = lk[w] > K ? lk[w] : K;
        }
        const int e = (HW - 1) - (int)(K & 0xFFFFFFFFull);
        const float mx = (float)(e >> 6);
        const float my = (float)(e & 63);
        const float loss = (mx * mx + my * my) * S0 - 2.f * mx * Sj - 2.f * my * Sk + Sq;
        ws[b] = loss;
    }
}

__global__ __launch_bounds__(256) void final_reduce(const float* __restrict__ ws,
                                                    float* __restrict__ out) {
    const int t = threadIdx.x;
    float s = 0.f;
#pragma unroll
    for (int i = 0; i < NB / 256; ++i) s += ws[i * 256 + t];
#pragma unroll
    for (int off = 32; off > 0; off >>= 1) s += __shfl_down(s, off);
    __shared__ float l[4];
    if ((t & 63) == 0) l[t >> 6] = s;
    __syncthreads();
    if (t == 0) out[0] = l[0] + l[1] + l[2] + l[3];
}

extern "C" void kernel_launch(void* const* d_in, const int* in_sizes, int n_in,
                              void* d_out, int out_size, void* d_ws, size_t ws_size,
                              hipStream_t stream) {
    const float* x = (const float*)d_in[0];
    float* out = (float*)d_out;
    float* ws  = (float*)d_ws;   // 8192 floats = 32 KiB of scratch

    per_sample_loss<<<NB, 256, 0, stream>>>(x, ws);
    final_reduce<<<1, 256, 0, stream>>>(ws, out);
}